// Round 1
// baseline (2013.231 us; speedup 1.0000x reference)
//
#include <hip/hip_runtime.h>

// ---------------------------------------------------------------------------
// Agent forward pass on MI355X — round 4.
//  * NEW: conv1/conv2/conv3/fc fused into the pipeline kernel as 2048
//    run-to-completion producer blocks (1 image each, whole chain in LDS).
//    Last finisher per 32-image t-slice does the fc GEMM and posts a per-t
//    hidden-ready flag; mem layer 0 waits on emb+fc (2 slots). This overlaps
//    the ~860us serial conv prologue with the latency-bound 437us LSTM scan
//    (which only occupies 84 of 256 CUs).
//  * LSTM weights pinned in AGPRs (inline-asm mfma, B operand "a").
//  * Activations staged global->LDS via global_load_lds dwordx4; h stored
//    chunk-XOR-swizzled in global so linear DMA yields conflict-free ds_read.
//  * Per-block flag slots + lane-parallel poll (no atomic-RMW serialization).
// ---------------------------------------------------------------------------

typedef __bf16 bf16;
typedef __bf16 bf16x8 __attribute__((ext_vector_type(8)));
typedef int v4i __attribute__((ext_vector_type(4)));
typedef float f32x4v __attribute__((ext_vector_type(4)));
typedef float f32x16v __attribute__((ext_vector_type(16)));
typedef unsigned int u32;

#define SCOPE_AGENT __HIP_MEMORY_SCOPE_AGENT
#define HM_ELEMS (65 * 32 * 512)

// MFMA via asm so B can live in AGPR. s_nop 2 covers VALU->MFMA SrcA/SrcC.
#define MFMA_AB(acc_, va_, wa_) \
  asm("s_nop 2\n\tv_mfma_f32_32x32x16_bf16 %0, %1, %2, %0" \
      : "+v"(acc_) : "v"(va_), "a"(wa_))
// Tie hazard nops to acc before VALU reads the MFMA result.
#define ACC_SYNC(acc_) asm volatile("s_nop 7\n\ts_nop 7" : "+v"(acc_))
// Pin a 4-dword value into the AGPR file.
#define PIN_A(x_) asm volatile("" : "+a"(x_))

__device__ __forceinline__ float sigf_(float x) {
  x = fminf(fmaxf(x, -30.f), 30.f);
  return 1.f / (1.f + __expf(-x));
}
__device__ __forceinline__ float tanhf_(float x) {
  x = fminf(fmaxf(x, -15.f), 15.f);
  float e = __expf(2.f * x);
  return (e - 1.f) / (e + 1.f);
}

__device__ __forceinline__ void async16(const bf16* g, bf16* l) {
  __builtin_amdgcn_global_load_lds(
      (const __attribute__((address_space(1))) u32*)g,
      (__attribute__((address_space(3))) u32*)l, 16, 0, 0);
}

// wave0 polls n flag slots (one dword each) until all nonzero.
__device__ __forceinline__ void wait_slots(int* f, int n, int tid) {
  if (tid < 64) {
    while (true) {
      int v = (tid < n) ? __hip_atomic_load(f + tid, __ATOMIC_RELAXED, SCOPE_AGENT) : 1;
      if (__all(v != 0)) break;
      __builtin_amdgcn_s_sleep(2);
    }
  }
}
__device__ __forceinline__ void post_slot(int* f) {
  __hip_atomic_store(f, 1, __ATOMIC_RELAXED, SCOPE_AGENT);
}
__device__ __forceinline__ void store_pair_at(bf16* base, size_t elem_idx, float a, float b) {
  unsigned short lo = __builtin_bit_cast(unsigned short, (bf16)a);
  unsigned short hi = __builtin_bit_cast(unsigned short, (bf16)b);
  u32 pk = (u32)lo | ((u32)hi << 16);
  __hip_atomic_store((u32*)base + (elem_idx >> 1), pk, __ATOMIC_RELAXED, SCOPE_AGENT);
}

// ---------------------------------------------------------------------------
// LSTM scan block. KREG regions of RDIM K each (mem: x+h = 2x512; enc: 1x256).
// Block owns 32 units (128 gate cols = 4 MFMA N-tiles). 4 waves K-split.
// Weights AGPR-resident. h global layout: [slot][32 m][RDIM] with 8-elem
// chunks XOR-swizzled by (m&7) so LDS copy is ds_read-friendly.
// ---------------------------------------------------------------------------
template<int KREG, int RDIM, bool PRE>
__device__ void scan_body(const bf16* __restrict__ Wrows, const float* __restrict__ biasf,
    const bf16* __restrict__ xbase, const bf16* __restrict__ hbase, bf16* __restrict__ hout,
    const float* __restrict__ cinit, const float* __restrict__ done,
    int* flag_own, int nslot_own, int* flag_x, int nslot_x, int myslot,
    int u0, int tid, char* smem)
{
  constexpr int KW = KREG * RDIM;
  constexpr int NKS = KW / 64;          // k-tiles per wave (mem 16, enc 4)
  constexpr int NI = RDIM / 16;         // load_lds instrs per region
  bf16* Abuf = (bf16*)smem;                                   // [KREG][32][RDIM]
  float* partial = (float*)(smem + KREG * 32 * RDIM * 2);     // [4][128][33]
  float* cl = partial + 4 * 128 * 33;                          // [32 m][32 u]
  const int lane = tid & 63, wv = tid >> 6;
  const int hsel = lane >> 5, ln31 = lane & 31;
  const int ks0 = wv * NKS;

  // ---- preload weights into AGPRs (time-invariant) ----
  v4i Wreg[4][NKS];
#pragma unroll
  for (int g = 0; g < 4; ++g) {
    int row = g * RDIM + u0 + ln31;
#pragma unroll
    for (int ks = 0; ks < NKS; ++ks) {
      Wreg[g][ks] = *(const v4i*)(Wrows + (size_t)row * KW + (ks0 + ks) * 16 + hsel * 8);
      PIN_A(Wreg[g][ks]);
    }
  }
  for (int i = tid; i < 1024; i += 256)
    cl[i] = cinit[(i >> 5) * RDIM + u0 + (i & 31)];

  for (int t = 0; t < 64; ++t) {
    if (t > 0) wait_slots(flag_own + (t - 1) * 16, nslot_own, tid);
    if (nslot_x > 0) wait_slots(flag_x + t * 16, nslot_x, tid);
    __syncthreads();
    // ---- stage activations: linear global -> LDS DMA ----
    for (int i = wv; i < KREG * NI; i += 4) {
      int r = i / NI, ii = i - r * NI;
      const bf16* src = (KREG == 2 && r == 0) ? xbase : hbase;
      async16(src + (size_t)t * 32 * RDIM + ii * 512 + lane * 8,
              Abuf + r * 32 * RDIM + ii * 512);
    }
    __syncthreads();

    const bool dmask = done[t * 32 + ln31] != 0.0f;
    f32x16v acc[4] = {};
#pragma unroll
    for (int ks = 0; ks < NKS; ++ks) {
      int kg = (ks0 + ks) * 16 + hsel * 8;
      int r = kg / RDIM, kk = kg - r * RDIM;
      v4i a = *(const v4i*)(Abuf + r * 32 * RDIM + ln31 * RDIM +
                            ((((kk >> 3) ^ (ln31 & 7)) << 3)));
      if (r == KREG - 1 && dmask) a = v4i{0, 0, 0, 0};
#pragma unroll
      for (int g = 0; g < 4; ++g)
        MFMA_AB(acc[g], a, Wreg[g][ks]);
    }
    ACC_SYNC(acc[0]); ACC_SYNC(acc[1]); ACC_SYNC(acc[2]); ACC_SYNC(acc[3]);
    // partial[wv][col=g*32+ln31][m]; C/D: col=lane&31, m=(reg&3)+8*(reg>>2)+4*hsel
#pragma unroll
    for (int g = 0; g < 4; ++g) {
      float* pp = partial + (wv * 128 + g * 32 + ln31) * 33 + 4 * hsel;
#pragma unroll
      for (int q = 0; q < 4; ++q)
#pragma unroll
        for (int s = 0; s < 4; ++s)
          pp[8 * q + s] = acc[g][4 * q + s];
    }
    __syncthreads();
    // pointwise: 32 m x 16 unit-pairs
    for (int p = tid; p < 512; p += 256) {
      int m = p >> 4, up = (p & 15) * 2;
      float dn = done[t * 32 + m];
      float hv[2];
#pragma unroll
      for (int j = 0; j < 2; ++j) {
        int u = up + j;
        float gg[4];
#pragma unroll
        for (int g = 0; g < 4; ++g) {
          int col = g * 32 + u;
          float s = partial[col * 33 + m] + partial[(128 + col) * 33 + m]
                  + partial[(256 + col) * 33 + m] + partial[(384 + col) * 33 + m];
          if (PRE) s += biasf[(size_t)(t * 32 + m) * (4 * RDIM) + g * RDIM + u0 + u];
          else     s += biasf[g * RDIM + u0 + u];
          gg[g] = s;
        }
        int ci = m * 32 + u;
        float cold = cl[ci] * (1.0f - dn);
        float cn = sigf_(gg[1]) * cold + sigf_(gg[0]) * tanhf_(gg[2]);
        cl[ci] = cn;
        hv[j] = sigf_(gg[3]) * tanhf_(cn);
      }
      int k = u0 + up;
      int pos = ((((k >> 3) ^ (m & 7)) << 3)) + (k & 7);
      store_pair_at(hout, ((size_t)(t + 1) * 32 + m) * RDIM + pos, hv[0], hv[1]);
    }
    __syncthreads();
    if (tid == 0) post_slot(flag_own + t * 16 + myslot);
  }
}

// ---- emb: lang_e[t] = relu(lang_h[t] @ emb_w.T + emb_b) -> hidden[:,256:288]
__device__ void emb_body(const bf16* __restrict__ Wemb, const float* __restrict__ emb_b,
    const bf16* __restrict__ h_enc, bf16* __restrict__ hidden,
    int* fle, int* flb, int t0, int tid, char* smem)
{
  bf16* Abuf = (bf16*)smem;                         // [32][256] (enc swizzle)
  float* partial = (float*)(smem + 32 * 256 * 2);   // [4][32][33]
  const int lane = tid & 63, wv = tid >> 6;
  const int hsel = lane >> 5, ln31 = lane & 31;
  const int ks0 = wv * 4;
  bf16x8 Wreg[4];
#pragma unroll
  for (int ks = 0; ks < 4; ++ks)
    Wreg[ks] = *(const bf16x8*)(Wemb + ln31 * 256 + (ks0 + ks) * 16 + hsel * 8);
  for (int t = t0; t < 64; t += 4) {
    wait_slots(fle + t * 16, 8, tid);
    __syncthreads();
    // copy (layout-preserving) h_enc slot t+1 into LDS
    {
      const uint4* s = (const uint4*)(h_enc + (size_t)(t + 1) * 32 * 256);
      for (int i = tid; i < 1024; i += 256) ((uint4*)Abuf)[i] = s[i];
    }
    __syncthreads();
    f32x16v acc = {};
#pragma unroll
    for (int ks = 0; ks < 4; ++ks) {
      int k = (ks0 + ks) * 16 + hsel * 8;
      bf16x8 a = *(const bf16x8*)(Abuf + ln31 * 256 + ((((k >> 3) ^ (ln31 & 7)) << 3)));
      acc = __builtin_amdgcn_mfma_f32_32x32x16_bf16(a, Wreg[ks], acc, 0, 0, 0);
    }
    float* pp = partial + (wv * 32 + ln31) * 33 + 4 * hsel;
#pragma unroll
    for (int q = 0; q < 4; ++q)
#pragma unroll
      for (int s = 0; s < 4; ++s)
        pp[8 * q + s] = acc[4 * q + s];
    __syncthreads();
    for (int p = tid; p < 512; p += 256) {
      int m = p >> 4, np = (p & 15) * 2;
      float v[2];
#pragma unroll
      for (int j = 0; j < 2; ++j) {
        int col = np + j;
        float s = partial[col * 33 + m] + partial[(32 + col) * 33 + m]
                + partial[(64 + col) * 33 + m] + partial[(96 + col) * 33 + m] + emb_b[col];
        v[j] = fmaxf(s, 0.f);
      }
      int k = 256 + np;
      int pos = ((((k >> 3) ^ (m & 7)) << 3)) + (k & 7);
      store_pair_at(hidden, (size_t)(t * 32 + m) * 512 + pos, v[0], v[1]);
    }
    __syncthreads();
    if (tid == 0) post_slot(flb + t * 16);   // slot 0: lang-emb half ready
  }
}

// ---- heads: logits, log_softmax, entropy, value
__device__ void heads_body(const bf16* __restrict__ h3, const float* __restrict__ actor_w,
    const float* __restrict__ actor_b, const float* __restrict__ critic_w,
    const float* __restrict__ critic_b, const int* __restrict__ action,
    float* __restrict__ out, int* fl3, int t0, int tid, char* smem)
{
  float* hS = (float*)smem;       // [32][520]
  float* lg = hS + 32 * 520;      // [32][8]
  float* vp = lg + 256;           // [32][8]
  const int b = tid >> 3, c = tid & 7;
  for (int t = t0; t < 64; t += 8) {
    wait_slots(fl3 + t * 16, 16, tid);
    __syncthreads();
    for (int i = tid; i < 2048; i += 256) {
      int m = i >> 6, j = i & 63;   // logical chunk j
      bf16x8 v = *(const bf16x8*)(h3 + ((size_t)(t + 1) * 32 + m) * 512 +
                                  ((j ^ (m & 7)) << 3));
#pragma unroll
      for (int q = 0; q < 8; ++q) hS[m * 520 + j * 8 + q] = (float)v[q];
    }
    __syncthreads();
    float acc = actor_b[c];
    float va = 0.f;
#pragma unroll 4
    for (int k = 0; k < 512; k += 4) {
      f32x4v hv = *(const f32x4v*)(hS + b * 520 + k);
      f32x4v wv4 = *(const f32x4v*)(actor_w + c * 512 + k);
      acc += hv[0]*wv4[0] + hv[1]*wv4[1] + hv[2]*wv4[2] + hv[3]*wv4[3];
    }
    for (int k = c * 64; k < c * 64 + 64; k += 4) {
      f32x4v hv = *(const f32x4v*)(hS + b * 520 + k);
      f32x4v wv4 = *(const f32x4v*)(critic_w + k);
      va += hv[0]*wv4[0] + hv[1]*wv4[1] + hv[2]*wv4[2] + hv[3]*wv4[3];
    }
    lg[b * 8 + c] = acc;
    vp[b * 8 + c] = va;
    __syncthreads();
    if (tid < 32) {
      const float* L = lg + tid * 8;
      float mx = L[0];
#pragma unroll
      for (int i = 1; i < 8; ++i) mx = fmaxf(mx, L[i]);
      float s = 0.f;
#pragma unroll
      for (int i = 0; i < 8; ++i) s += __expf(L[i] - mx);
      float lse = mx + __logf(s);
      float ent = 0.f;
#pragma unroll
      for (int i = 0; i < 8; ++i) { float lp = L[i] - lse; ent -= __expf(lp) * lp; }
      int a = action[t * 32 + tid];
      a = a < 0 ? 0 : (a > 7 ? 7 : a);
      float val = critic_b[0];
#pragma unroll
      for (int i = 0; i < 8; ++i) val += vp[tid * 8 + i];
      float* o = out + (size_t)(t * 32 + tid) * 3;
      o[0] = L[a] - lse; o[1] = ent; o[2] = val;
    }
    __syncthreads();
  }
}

// ---------------------------------------------------------------------------
// fc for one t-slice (32 images): hidden[t*32..t*32+32, 0:256] =
//   relu(a3bf[t*32.., :1568] @ fcwbf.T + fc_b). MFMA 32x32x16, Kc=112 (14 it).
// Executed by the LAST conv-chain finisher of the slice. Posts slot 1.
// ---------------------------------------------------------------------------
__device__ void fc_slice(int t, const bf16* __restrict__ a3bf,
    const bf16* __restrict__ wbf, const float* __restrict__ fc_b,
    bf16* __restrict__ hidden, int* flb, int tid, char* smem)
{
  bf16* sA = (bf16*)smem;                 // [32][112]   7168 B
  bf16* sB = sA + 32 * 112;               // [256][112]  57344 B (ends 64512)
  float* hidF = (float*)(smem + 65536);   // [32][256]   32 KB
  const int lane = tid & 63, wv = tid >> 6, hsel = lane >> 5, ln31 = lane & 31;
  f32x16v acc0 = {}, acc1 = {};
  for (int kb = 0; kb < 1568; kb += 112) {
    __syncthreads();
    for (int i = tid; i < 448; i += 256) {
      int r = i / 14, kk = (i % 14) * 8;
      *(bf16x8*)(sA + r * 112 + kk) =
          *(const bf16x8*)(a3bf + ((size_t)(t * 32 + r)) * 1568 + kb + kk);
    }
    for (int i = tid; i < 3584; i += 256) {
      int c = i / 14, kk = (i % 14) * 8;
      *(bf16x8*)(sB + c * 112 + kk) =
          *(const bf16x8*)(wbf + (size_t)c * 1568 + kb + kk);
    }
    __syncthreads();
#pragma unroll
    for (int kt = 0; kt < 7; ++kt) {
      int k = kt * 16 + hsel * 8;
      bf16x8 a  = *(const bf16x8*)(sA + ln31 * 112 + k);
      bf16x8 b0 = *(const bf16x8*)(sB + (wv * 64 + ln31) * 112 + k);
      bf16x8 b1 = *(const bf16x8*)(sB + (wv * 64 + 32 + ln31) * 112 + k);
      acc0 = __builtin_amdgcn_mfma_f32_32x32x16_bf16(a, b0, acc0, 0, 0, 0);
      acc1 = __builtin_amdgcn_mfma_f32_32x32x16_bf16(a, b1, acc1, 0, 0, 0);
    }
  }
  // C/D: col = lane&31 (B rows = output cols), m = 8q+4hsel+s (A rows = images)
  float bv0 = fc_b[wv * 64 + ln31];
  float bv1 = fc_b[wv * 64 + 32 + ln31];
#pragma unroll
  for (int q = 0; q < 4; ++q)
#pragma unroll
    for (int s = 0; s < 4; ++s) {
      int m = 8 * q + 4 * hsel + s;
      hidF[m * 256 + wv * 64 + ln31]      = fmaxf(acc0[4 * q + s] + bv0, 0.f);
      hidF[m * 256 + wv * 64 + 32 + ln31] = fmaxf(acc1[4 * q + s] + bv1, 0.f);
    }
  __syncthreads();
  for (int i = tid; i < 4096; i += 256) {          // 32 m x 128 col-pairs
    int m = i >> 7, j = (i & 127) * 2;
    int pos = (((j >> 3) ^ (m & 7)) << 3) + (j & 7);
    store_pair_at(hidden, ((size_t)(t * 32 + m)) * 512 + pos,
                  hidF[m * 256 + j], hidF[m * 256 + j + 1]);
  }
  __syncthreads();
  if (tid == 0) post_slot(flb + t * 16 + 1);       // slot 1: img half ready
}

// ---------------------------------------------------------------------------
// producer chain: conv1(MFMA) -> conv2 -> conv3 for ONE image, all in LDS;
// pack A3 row (bf16, atomic-store) -> a3bf; last finisher of slice does fc.
// LDS map: [0,64K) sP / sW2(0..18K)+sW3(18K..54K) / sA+sB(0..63K)
//          [64K..) A1L(7.7K) A2L(10.4K) A3L(6.3K)  | fc: hidF(64K..96K)
//          lastF @ 132K
// ---------------------------------------------------------------------------
__device__ void chain_body(int n, const float* __restrict__ img,
    const bf16* __restrict__ w1bf, const float* __restrict__ c1b,
    const float* __restrict__ c2w, const float* __restrict__ c2b,
    const float* __restrict__ c3w, const float* __restrict__ c3b,
    const bf16* __restrict__ fcwbf, const float* __restrict__ fc_b,
    bf16* __restrict__ a3bf, bf16* __restrict__ hidden,
    int* cnt, int* flb, int tid, char* smem)
{
  const int lane = tid & 63, wv = tid >> 6;
  bf16* sP = (bf16*)smem;                       // [128][256] 64 KB
  float* A1L = (float*)(smem + 65536);          // 16*121
  float* A2L = A1L + 16 * 121;                  // 32*81
  float* A3L = A2L + 32 * 81;                   // 1568
  // ---- conv1: stride 9 == kernel 9 -> disjoint patches as 16x16x32 MFMA ----
  for (int i = tid; i < 4096; i += 256) ((uint4*)sP)[i] = uint4{0u, 0u, 0u, 0u};
  __syncthreads();
  const float* ib = img + (size_t)n * 29403;
  for (int e = tid; e < 29403; e += 256) {
    int c = e / 9801, r = e - c * 9801;
    int h = r / 99, w = r - h * 99;
    int oh = h / 9, kh = h - oh * 9;
    int ow = w / 9, kw = w - ow * 9;
    int p = oh * 11 + ow;
    int k = c * 81 + kh * 9 + kw;
    sP[p * 256 + (k ^ ((p & 15) * 8))] = (bf16)ib[e];
  }
  __syncthreads();
  {
    const int oc = lane & 15, kg = lane >> 4;
    bf16x8 bfr[8];
#pragma unroll
    for (int ks = 0; ks < 8; ++ks)
      bfr[ks] = *(const bf16x8*)(w1bf + oc * 256 + ks * 32 + kg * 8);
    const float bv = c1b[oc];
#pragma unroll
    for (int mt2 = 0; mt2 < 2; ++mt2) {
      int mt = wv * 2 + mt2;
      int p = mt * 16 + (lane & 15);
      f32x4v acc = {};
#pragma unroll
      for (int ks = 0; ks < 8; ++ks) {
        int k0 = ks * 32 + kg * 8;
        bf16x8 a = *(const bf16x8*)(sP + p * 256 + (k0 ^ ((p & 15) * 8)));
        acc = __builtin_amdgcn_mfma_f32_16x16x32_bf16(a, bfr[ks], acc, 0, 0, 0);
      }
#pragma unroll
      for (int s = 0; s < 4; ++s) {
        int pm = mt * 16 + (lane >> 4) * 4 + s;
        if (pm < 121) A1L[oc * 121 + pm] = fmaxf(acc[s] + bv, 0.f);
      }
    }
  }
  __syncthreads();
  // ---- conv2 (register-tiled, input already in LDS) ----
  float* sW2 = (float*)smem;                    // 4608 f (sP dead)
  for (int i = tid; i < 4608; i += 256) sW2[i] = c2w[i];
  __syncthreads();
  for (int task = tid; task < 288; task += 256) {
    int oc = task & 31, oh = task >> 5;
    float acc[9];
    float bv = c2b[oc];
#pragma unroll
    for (int ow = 0; ow < 9; ++ow) acc[ow] = bv;
    for (int c = 0; c < 16; ++c) {
      const float* wr = sW2 + oc * 144 + c * 9;
      float wq[9];
#pragma unroll
      for (int q = 0; q < 9; ++q) wq[q] = wr[q];
#pragma unroll
      for (int kh = 0; kh < 3; ++kh) {
        const float* ir = A1L + c * 121 + (oh + kh) * 11;
        float iv[11];
#pragma unroll
        for (int q = 0; q < 11; ++q) iv[q] = ir[q];
#pragma unroll
        for (int ow = 0; ow < 9; ++ow)
          acc[ow] += wq[kh*3]*iv[ow] + wq[kh*3+1]*iv[ow+1] + wq[kh*3+2]*iv[ow+2];
      }
    }
#pragma unroll
    for (int ow = 0; ow < 9; ++ow)
      A2L[oc * 81 + oh * 9 + ow] = fmaxf(acc[ow], 0.f);
  }
  __syncthreads();
  // ---- conv3 ----
  float* sW3 = (float*)smem + 4608;             // 9216 f @ [18432, 55296)
  for (int i = tid; i < 9216; i += 256) sW3[i] = c3w[i];
  __syncthreads();
  for (int task = tid; task < 224; task += 256) {
    int oc = task & 31, oh = task >> 5;
    float acc[7];
    float bv = c3b[oc];
#pragma unroll
    for (int ow = 0; ow < 7; ++ow) acc[ow] = bv;
    for (int c = 0; c < 32; ++c) {
      const float* wr = sW3 + oc * 288 + c * 9;
      float wq[9];
#pragma unroll
      for (int q = 0; q < 9; ++q) wq[q] = wr[q];
#pragma unroll
      for (int kh = 0; kh < 3; ++kh) {
        const float* ir = A2L + c * 81 + (oh + kh) * 9;
        float iv[9];
#pragma unroll
        for (int q = 0; q < 9; ++q) iv[q] = ir[q];
#pragma unroll
        for (int ow = 0; ow < 7; ++ow)
          acc[ow] += wq[kh*3]*iv[ow] + wq[kh*3+1]*iv[ow+1] + wq[kh*3+2]*iv[ow+2];
      }
    }
#pragma unroll
    for (int ow = 0; ow < 7; ++ow)
      A3L[oc * 49 + oh * 7 + ow] = fmaxf(acc[ow], 0.f);
  }
  __syncthreads();
  // ---- pack A3 row -> global bf16 (atomic-store pattern, same as h) ----
  for (int i = tid; i < 784; i += 256)
    store_pair_at(a3bf, (size_t)n * 1568 + 2 * i, A3L[2 * i], A3L[2 * i + 1]);
  __syncthreads();
  int* lastF = (int*)(smem + 135168);
  if (tid == 0)
    *lastF = __hip_atomic_fetch_add(cnt + (n >> 5), 1, __ATOMIC_ACQ_REL, SCOPE_AGENT);
  __syncthreads();
  if (*lastF != 31) return;
  fc_slice(n >> 5, a3bf, fcwbf, fc_b, hidden, flb, tid, smem);
}

struct PipeP {
  const bf16 *Wenc, *Wm0, *Wm1, *Wm2, *Wm3, *Wemb;
  const float *pre_enc, *bc, *done, *emb_b, *enc_c0, *mem_c0;
  bf16 *hidden, *h_enc, *h_mem;
  const float *actor_w, *actor_b, *critic_w, *critic_b;
  const int *action;
  float *out;
  int *fl;
  // producer side
  const float *img, *c1b, *c2w, *c2b, *c3w, *c3b, *fc_b;
  const bf16 *w1bf, *fcwbf;
  bf16 *a3bf;
  int *cnt;
};

// flag ints: mem l: (l*64+t)*16+s (16 slots); enc: (256+t)*16+s (8);
// hidden-ready: (320+t)*16 + {0:emb, 1:fc}
// grid: 0..63 mem (16 x 4 layers), 64..71 enc, 72..75 emb, 76..83 heads,
//       84..2131 conv/fc producer chains (image n = bid-84). Producers are
//       run-to-completion (no waits) -> deadlock-free under any dispatch order.
__global__ __launch_bounds__(256, 1) void pipeline_kernel(PipeP P) {
  extern __shared__ char smem[];
  const int bid = blockIdx.x, tid = threadIdx.x;
  int* fl = P.fl;
  if (bid < 64) {
    int l = bid >> 4, s = bid & 15, u0 = s * 32;
    bf16* hown = P.h_mem + (size_t)l * HM_ELEMS;
    const bf16* W = (l == 0) ? P.Wm0 : (l == 1) ? P.Wm1 : (l == 2) ? P.Wm2 : P.Wm3;
    const bf16* xb = (l == 0) ? P.hidden : P.h_mem + (size_t)(l - 1) * HM_ELEMS + 32 * 512;
    int* fown = fl + l * 1024;
    int* fx = (l == 0) ? fl + 320 * 16 : fl + (l - 1) * 1024;
    int nx = (l == 0) ? 2 : 16;     // l0 waits emb(slot0) + fc(slot1)
    scan_body<2, 512, false>(W, P.bc + l * 2048, xb, hown, hown,
        P.mem_c0 + l * 32 * 512, P.done, fown, 16, fx, nx, s, u0, tid, smem);
  } else if (bid < 72) {
    int s = bid - 64, u0 = s * 32;
    scan_body<1, 256, true>(P.Wenc, P.pre_enc, nullptr, P.h_enc, P.h_enc,
        P.enc_c0, P.done, fl + 256 * 16, 8, nullptr, 0, s, u0, tid, smem);
  } else if (bid < 76) {
    emb_body(P.Wemb, P.emb_b, P.h_enc, P.hidden, fl + 256 * 16, fl + 320 * 16,
             bid - 72, tid, smem);
  } else if (bid < 84) {
    heads_body(P.h_mem + 3ull * HM_ELEMS, P.actor_w, P.actor_b, P.critic_w, P.critic_b,
        P.action, P.out, fl + 3 * 1024, bid - 76, tid, smem);
  } else {
    chain_body(bid - 84, P.img, P.w1bf, P.c1b, P.c2w, P.c2b, P.c3w, P.c3b,
               P.fcwbf, P.fc_b, P.a3bf, P.hidden, P.cnt, fl + 320 * 16, tid, smem);
  }
}

// ---------------------------------------------------------------------------
// prep: vectorized (8 elems/thread) weight conversions / swizzled h0 slots
// ---------------------------------------------------------------------------
__device__ __forceinline__ void cvt_store8(bf16* dst, const float* src) {
  f32x4v a = *(const f32x4v*)src, b = *(const f32x4v*)(src + 4);
  bf16x8 o;
#pragma unroll
  for (int j = 0; j < 4; ++j) { o[j] = (bf16)a[j]; o[4 + j] = (bf16)b[j]; }
  *(bf16x8*)dst = o;
}

__global__ void prep_kernel(
    const float* __restrict__ enc_Whh, const float* __restrict__ mem_Wih0,
    const float* __restrict__ mem_WihR, const float* __restrict__ mem_Whh,
    const float* __restrict__ emb_w, const float* __restrict__ mem_bih,
    const float* __restrict__ mem_bhh, const float* __restrict__ enc_h0,
    const float* __restrict__ mem_h0, const float* __restrict__ fc_w,
    const float* __restrict__ conv1_w,
    bf16* __restrict__ Wenc, bf16* __restrict__ Wm0, bf16* __restrict__ Wm123,
    bf16* __restrict__ Wemb, float* __restrict__ bc,
    bf16* __restrict__ h_enc, bf16* __restrict__ h_mem, bf16* __restrict__ fcw_bf,
    bf16* __restrict__ w1bf)
{
  int v = blockIdx.x * 256 + threadIdx.x;   // 8-elem vector index
  if (v < 32768) { cvt_store8(Wenc + v * 8, enc_Whh + v * 8); return; }
  v -= 32768;
  if (v < 262144) {   // Wm0 [2048 cols][1024 k]: 288 Wih0 | 224 zero | 512 Whh
    int col = v >> 7, c = v & 127;
    bf16x8 o = {};
    if (c < 36) {
      const float* s = mem_Wih0 + col * 288 + c * 8;
#pragma unroll
      for (int j = 0; j < 8; ++j) o[j] = (bf16)s[j];
    } else if (c >= 64) {
      const float* s = mem_Whh + col * 512 + (c - 64) * 8;
#pragma unroll
      for (int j = 0; j < 8; ++j) o[j] = (bf16)s[j];
    }
    *(bf16x8*)(Wm0 + (size_t)v * 8) = o;
    return;
  }
  v -= 262144;
  if (v < 786432) {   // Wm1..3 [l][2048 cols][1024 k]: 512 WihR | 512 Whh
    int l = v >> 18, r = v & 262143, col = r >> 7, c = r & 127;
    const float* s = (c < 64) ? mem_WihR + ((size_t)(l * 2048 + col)) * 512 + c * 8
                              : mem_Whh + ((size_t)((l + 1) * 2048 + col)) * 512 + (c - 64) * 8;
    cvt_store8(Wm123 + (size_t)v * 8, s);
    return;
  }
  v -= 786432;
  if (v < 1024) { cvt_store8(Wemb + v * 8, emb_w + v * 8); return; }
  v -= 1024;
  if (v < 1024) {
#pragma unroll
    for (int j = 0; j < 8; ++j) bc[v * 8 + j] = mem_bih[v * 8 + j] + mem_bhh[v * 8 + j];
    return;
  }
  v -= 1024;
  if (v < 1024) {     // h_enc slot 0 (swizzled)
    int m = v >> 5, c = v & 31;
    bf16x8 o;
    const float* s = enc_h0 + m * 256 + c * 8;
#pragma unroll
    for (int j = 0; j < 8; ++j) o[j] = (bf16)s[j];
    *(bf16x8*)(h_enc + m * 256 + ((c ^ (m & 7)) << 3)) = o;
    return;
  }
  v -= 1024;
  if (v < 8192) {     // h_mem slot 0 per layer (swizzled)
    int l = v >> 11, r = v & 2047, m = r >> 6, c = r & 63;
    bf16x8 o;
    const float* s = mem_h0 + ((size_t)(l * 32 + m)) * 512 + c * 8;
#pragma unroll
    for (int j = 0; j < 8; ++j) o[j] = (bf16)s[j];
    *(bf16x8*)(h_mem + (size_t)l * HM_ELEMS + m * 512 + ((c ^ (m & 7)) << 3)) = o;
    return;
  }
  v -= 8192;
  if (v < 50176) { cvt_store8(fcw_bf + (size_t)v * 8, fc_w + (size_t)v * 8); return; }
  v -= 50176;
  if (v < 512) {      // conv1 weights [16 oc][256 k] zero-padded
    int oc = v >> 5, c = v & 31;
    bf16x8 o = {};
#pragma unroll
    for (int j = 0; j < 8; ++j) {
      int k = c * 8 + j;
      if (k < 243) o[j] = (bf16)conv1_w[oc * 243 + k];
    }
    *(bf16x8*)(w1bf + v * 8) = o;
    return;
  }
}

__global__ void pre_enc_kernel(const float* __restrict__ lang, const float* __restrict__ Wih,
    const float* __restrict__ bih, const float* __restrict__ bhh, float* __restrict__ pre)
{
  int idx = blockIdx.x * 256 + threadIdx.x;
  if (idx >= 64 * 32 * 1024) return;
  int col = idx & 1023, bm = idx >> 10;
  float acc = bih[col] + bhh[col];
  const float* lp = lang + bm * 14;
  const float* wp = Wih + col * 14;
#pragma unroll
  for (int k = 0; k < 14; ++k) acc += lp[k] * wp[k];
  pre[idx] = acc;
}

// ---------------------------------------------------------------------------
extern "C" void kernel_launch(void* const* d_in, const int* in_sizes, int n_in,
                              void* d_out, int out_size, void* d_ws, size_t ws_size,
                              hipStream_t stream)
{
  const float* img      = (const float*)d_in[0];
  const float* lang     = (const float*)d_in[1];
  const float* done     = (const float*)d_in[2];
  const int*   action   = (const int*)d_in[3];
  const float* enc_h0   = (const float*)d_in[4];
  const float* enc_c0   = (const float*)d_in[5];
  const float* mem_h0   = (const float*)d_in[6];
  const float* mem_c0   = (const float*)d_in[7];
  const float* conv1_w  = (const float*)d_in[8];
  const float* conv1_b  = (const float*)d_in[9];
  const float* conv2_w  = (const float*)d_in[10];
  const float* conv2_b  = (const float*)d_in[11];
  const float* conv3_w  = (const float*)d_in[12];
  const float* conv3_b  = (const float*)d_in[13];
  const float* fc_w     = (const float*)d_in[14];
  const float* fc_b     = (const float*)d_in[15];
  const float* enc_Wih  = (const float*)d_in[16];
  const float* enc_Whh  = (const float*)d_in[17];
  const float* enc_bih  = (const float*)d_in[18];
  const float* enc_bhh  = (const float*)d_in[19];
  const float* emb_w    = (const float*)d_in[20];
  const float* emb_b    = (const float*)d_in[21];
  const float* mem_Wih0 = (const float*)d_in[22];
  const float* mem_WihR = (const float*)d_in[23];
  const float* mem_Whh  = (const float*)d_in[24];
  const float* mem_bih  = (const float*)d_in[25];
  const float* mem_bhh  = (const float*)d_in[26];
  const float* actor_w  = (const float*)d_in[27];
  const float* actor_b  = (const float*)d_in[28];
  const float* critic_w = (const float*)d_in[29];
  const float* critic_b = (const float*)d_in[30];
  float* out = (float*)d_out;
  (void)in_sizes; (void)n_in; (void)out_size; (void)ws_size;

  char* wp = (char*)d_ws;
  auto alloc = [&](size_t b) { char* p = wp; wp += (b + 255) & ~(size_t)255; return p; };
  bf16*  hidden = (bf16*) alloc(2048ull * 512 * 2);          // [TB][512] swizzled, zero-pad
  float* preenc = (float*)alloc(64ull * 32 * 1024 * 4);
  bf16*  Wenc   = (bf16*) alloc(1024ull * 256 * 2);
  bf16*  Wm0    = (bf16*) alloc(2048ull * 1024 * 2);
  bf16*  Wm123  = (bf16*) alloc(3ull * 2048 * 1024 * 2);
  bf16*  Wemb   = (bf16*) alloc(32ull * 256 * 2);
  float* bc     = (float*)alloc(4ull * 2048 * 4);
  bf16*  h_enc  = (bf16*) alloc(65ull * 32 * 256 * 2);
  bf16*  h_mem  = (bf16*) alloc(4ull * HM_ELEMS * 2);
  bf16*  fcwbf  = (bf16*) alloc(256ull * 1568 * 2);
  bf16*  w1bf   = (bf16*) alloc(16ull * 256 * 2);
  bf16*  a3bf   = (bf16*) alloc(2048ull * 1568 * 2);         // conv3 output rows
  int*   fl     = (int*)  alloc(24832);                      // flags + cnt tail
  int*   cnt    = fl + 6144;                                 // [64] per-slice counters

  hipMemsetAsync(fl, 0, 24832, stream);
  hipMemsetAsync(hidden, 0, 2048ull * 512 * 2, stream);
  prep_kernel<<<4466, 256, 0, stream>>>(enc_Whh, mem_Wih0, mem_WihR, mem_Whh, emb_w,
      mem_bih, mem_bhh, enc_h0, mem_h0, fc_w, conv1_w,
      Wenc, Wm0, Wm123, Wemb, bc, h_enc, h_mem, fcwbf, w1bf);
  pre_enc_kernel<<<8192, 256, 0, stream>>>(lang, enc_Wih, enc_bih, enc_bhh, preenc);

  PipeP P;
  P.Wenc = Wenc; P.Wm0 = Wm0; P.Wm1 = Wm123;
  P.Wm2 = Wm123 + 2048ull * 1024; P.Wm3 = Wm123 + 2ull * 2048 * 1024;
  P.Wemb = Wemb; P.pre_enc = preenc; P.bc = bc; P.done = done; P.emb_b = emb_b;
  P.enc_c0 = enc_c0; P.mem_c0 = mem_c0; P.hidden = hidden; P.h_enc = h_enc; P.h_mem = h_mem;
  P.actor_w = actor_w; P.actor_b = actor_b; P.critic_w = critic_w; P.critic_b = critic_b;
  P.action = action; P.out = out; P.fl = fl;
  P.img = img; P.c1b = conv1_b; P.c2w = conv2_w; P.c2b = conv2_b;
  P.c3w = conv3_w; P.c3b = conv3_b; P.fc_b = fc_b;
  P.w1bf = w1bf; P.fcwbf = fcwbf; P.a3bf = a3bf; P.cnt = cnt;

  (void)hipFuncSetAttribute((const void*)pipeline_kernel,
      hipFuncAttributeMaxDynamicSharedMemorySize, 137216);
  pipeline_kernel<<<84 + 2048, 256, 137216, stream>>>(P);
}

// Round 2
// 1202.910 us; speedup vs baseline: 1.6736x; 1.6736x over previous
//
#include <hip/hip_runtime.h>

// ---------------------------------------------------------------------------
// Agent forward pass on MI355X — round 5.
//  * REVERT round-4 fusion: producers at 137KB uniform LDS ran 1 wave/SIMD
//    (occupancy 8.4%) with 172M LDS bank-conflict cycles -> 2013us. Back to
//    the 84-block pipeline + separate prologue (round-3 = 1300us base).
//  * NEW: conv2/conv3 LDS weight strides padded 144->145 / 288->297.
//    Old strides were 16-way / 32-way bank conflicts on EVERY weight load
//    (oc stride 144%32=16 -> 2 banks; 288%32=0 -> 1 bank). Odd bank strides
//    (17, 9) give 32 distinct banks -> conflict-free.
//  * NEW: conv2+conv3+fc fused in one kernel (A2 stays in LDS, last finisher
//    per 32-image slice runs the fc GEMM via cnt acq-rel, proven round 4).
//  * NEW: prep + pre_enc merged into one launch. 7 -> 5 launches.
//  * LSTM scan (AGPR-pinned weights, global_load_lds staging, flag pipeline)
//    unchanged from round 3.
// ---------------------------------------------------------------------------

typedef __bf16 bf16;
typedef __bf16 bf16x8 __attribute__((ext_vector_type(8)));
typedef int v4i __attribute__((ext_vector_type(4)));
typedef float f32x4v __attribute__((ext_vector_type(4)));
typedef float f32x16v __attribute__((ext_vector_type(16)));
typedef unsigned int u32;

#define SCOPE_AGENT __HIP_MEMORY_SCOPE_AGENT
#define HM_ELEMS (65 * 32 * 512)

// MFMA via asm so B can live in AGPR. s_nop 2 covers VALU->MFMA SrcA/SrcC.
#define MFMA_AB(acc_, va_, wa_) \
  asm("s_nop 2\n\tv_mfma_f32_32x32x16_bf16 %0, %1, %2, %0" \
      : "+v"(acc_) : "v"(va_), "a"(wa_))
// Tie hazard nops to acc before VALU reads the MFMA result.
#define ACC_SYNC(acc_) asm volatile("s_nop 7\n\ts_nop 7" : "+v"(acc_))
// Pin a 4-dword value into the AGPR file.
#define PIN_A(x_) asm volatile("" : "+a"(x_))

__device__ __forceinline__ float sigf_(float x) {
  x = fminf(fmaxf(x, -30.f), 30.f);
  return 1.f / (1.f + __expf(-x));
}
__device__ __forceinline__ float tanhf_(float x) {
  x = fminf(fmaxf(x, -15.f), 15.f);
  float e = __expf(2.f * x);
  return (e - 1.f) / (e + 1.f);
}

__device__ __forceinline__ void async16(const bf16* g, bf16* l) {
  __builtin_amdgcn_global_load_lds(
      (const __attribute__((address_space(1))) u32*)g,
      (__attribute__((address_space(3))) u32*)l, 16, 0, 0);
}

// wave0 polls n flag slots (one dword each) until all nonzero.
__device__ __forceinline__ void wait_slots(int* f, int n, int tid) {
  if (tid < 64) {
    while (true) {
      int v = (tid < n) ? __hip_atomic_load(f + tid, __ATOMIC_RELAXED, SCOPE_AGENT) : 1;
      if (__all(v != 0)) break;
      __builtin_amdgcn_s_sleep(2);
    }
  }
}
__device__ __forceinline__ void post_slot(int* f) {
  __hip_atomic_store(f, 1, __ATOMIC_RELAXED, SCOPE_AGENT);
}
__device__ __forceinline__ void store_pair_at(bf16* base, size_t elem_idx, float a, float b) {
  unsigned short lo = __builtin_bit_cast(unsigned short, (bf16)a);
  unsigned short hi = __builtin_bit_cast(unsigned short, (bf16)b);
  u32 pk = (u32)lo | ((u32)hi << 16);
  __hip_atomic_store((u32*)base + (elem_idx >> 1), pk, __ATOMIC_RELAXED, SCOPE_AGENT);
}

// ---------------------------------------------------------------------------
// LSTM scan block. KREG regions of RDIM K each (mem: x+h = 2x512; enc: 1x256).
// Block owns 32 units (128 gate cols = 4 MFMA N-tiles). 4 waves K-split.
// Weights AGPR-resident. h global layout: [slot][32 m][RDIM] with 8-elem
// chunks XOR-swizzled by (m&7) so LDS copy is ds_read-friendly.
// ---------------------------------------------------------------------------
template<int KREG, int RDIM, bool PRE>
__device__ void scan_body(const bf16* __restrict__ Wrows, const float* __restrict__ biasf,
    const bf16* __restrict__ xbase, const bf16* __restrict__ hbase, bf16* __restrict__ hout,
    const float* __restrict__ cinit, const float* __restrict__ done,
    int* flag_own, int nslot_own, int* flag_x, int nslot_x, int myslot,
    int u0, int tid, char* smem)
{
  constexpr int KW = KREG * RDIM;
  constexpr int NKS = KW / 64;          // k-tiles per wave (mem 16, enc 4)
  constexpr int NI = RDIM / 16;         // load_lds instrs per region
  bf16* Abuf = (bf16*)smem;                                   // [KREG][32][RDIM]
  float* partial = (float*)(smem + KREG * 32 * RDIM * 2);     // [4][128][33]
  float* cl = partial + 4 * 128 * 33;                          // [32 m][32 u]
  const int lane = tid & 63, wv = tid >> 6;
  const int hsel = lane >> 5, ln31 = lane & 31;
  const int ks0 = wv * NKS;

  // ---- preload weights into AGPRs (time-invariant) ----
  v4i Wreg[4][NKS];
#pragma unroll
  for (int g = 0; g < 4; ++g) {
    int row = g * RDIM + u0 + ln31;
#pragma unroll
    for (int ks = 0; ks < NKS; ++ks) {
      Wreg[g][ks] = *(const v4i*)(Wrows + (size_t)row * KW + (ks0 + ks) * 16 + hsel * 8);
      PIN_A(Wreg[g][ks]);
    }
  }
  for (int i = tid; i < 1024; i += 256)
    cl[i] = cinit[(i >> 5) * RDIM + u0 + (i & 31)];

  for (int t = 0; t < 64; ++t) {
    if (t > 0) wait_slots(flag_own + (t - 1) * 16, nslot_own, tid);
    if (nslot_x > 0) wait_slots(flag_x + t * 16, nslot_x, tid);
    __syncthreads();
    // ---- stage activations: linear global -> LDS DMA ----
    for (int i = wv; i < KREG * NI; i += 4) {
      int r = i / NI, ii = i - r * NI;
      const bf16* src = (KREG == 2 && r == 0) ? xbase : hbase;
      async16(src + (size_t)t * 32 * RDIM + ii * 512 + lane * 8,
              Abuf + r * 32 * RDIM + ii * 512);
    }
    __syncthreads();

    const bool dmask = done[t * 32 + ln31] != 0.0f;
    f32x16v acc[4] = {};
#pragma unroll
    for (int ks = 0; ks < NKS; ++ks) {
      int kg = (ks0 + ks) * 16 + hsel * 8;
      int r = kg / RDIM, kk = kg - r * RDIM;
      v4i a = *(const v4i*)(Abuf + r * 32 * RDIM + ln31 * RDIM +
                            ((((kk >> 3) ^ (ln31 & 7)) << 3)));
      if (r == KREG - 1 && dmask) a = v4i{0, 0, 0, 0};
#pragma unroll
      for (int g = 0; g < 4; ++g)
        MFMA_AB(acc[g], a, Wreg[g][ks]);
    }
    ACC_SYNC(acc[0]); ACC_SYNC(acc[1]); ACC_SYNC(acc[2]); ACC_SYNC(acc[3]);
    // partial[wv][col=g*32+ln31][m]; C/D: col=lane&31, m=(reg&3)+8*(reg>>2)+4*hsel
#pragma unroll
    for (int g = 0; g < 4; ++g) {
      float* pp = partial + (wv * 128 + g * 32 + ln31) * 33 + 4 * hsel;
#pragma unroll
      for (int q = 0; q < 4; ++q)
#pragma unroll
        for (int s = 0; s < 4; ++s)
          pp[8 * q + s] = acc[g][4 * q + s];
    }
    __syncthreads();
    // pointwise: 32 m x 16 unit-pairs
    for (int p = tid; p < 512; p += 256) {
      int m = p >> 4, up = (p & 15) * 2;
      float dn = done[t * 32 + m];
      float hv[2];
#pragma unroll
      for (int j = 0; j < 2; ++j) {
        int u = up + j;
        float gg[4];
#pragma unroll
        for (int g = 0; g < 4; ++g) {
          int col = g * 32 + u;
          float s = partial[col * 33 + m] + partial[(128 + col) * 33 + m]
                  + partial[(256 + col) * 33 + m] + partial[(384 + col) * 33 + m];
          if (PRE) s += biasf[(size_t)(t * 32 + m) * (4 * RDIM) + g * RDIM + u0 + u];
          else     s += biasf[g * RDIM + u0 + u];
          gg[g] = s;
        }
        int ci = m * 32 + u;
        float cold = cl[ci] * (1.0f - dn);
        float cn = sigf_(gg[1]) * cold + sigf_(gg[0]) * tanhf_(gg[2]);
        cl[ci] = cn;
        hv[j] = sigf_(gg[3]) * tanhf_(cn);
      }
      int k = u0 + up;
      int pos = ((((k >> 3) ^ (m & 7)) << 3)) + (k & 7);
      store_pair_at(hout, ((size_t)(t + 1) * 32 + m) * RDIM + pos, hv[0], hv[1]);
    }
    __syncthreads();
    if (tid == 0) post_slot(flag_own + t * 16 + myslot);
  }
}

// ---- emb: lang_e[t] = relu(lang_h[t] @ emb_w.T + emb_b) -> hidden[:,256:288]
__device__ void emb_body(const bf16* __restrict__ Wemb, const float* __restrict__ emb_b,
    const bf16* __restrict__ h_enc, bf16* __restrict__ hidden,
    int* fle, int* flb, int t0, int tid, char* smem)
{
  bf16* Abuf = (bf16*)smem;                         // [32][256] (enc swizzle)
  float* partial = (float*)(smem + 32 * 256 * 2);   // [4][32][33]
  const int lane = tid & 63, wv = tid >> 6;
  const int hsel = lane >> 5, ln31 = lane & 31;
  const int ks0 = wv * 4;
  bf16x8 Wreg[4];
#pragma unroll
  for (int ks = 0; ks < 4; ++ks)
    Wreg[ks] = *(const bf16x8*)(Wemb + ln31 * 256 + (ks0 + ks) * 16 + hsel * 8);
  for (int t = t0; t < 64; t += 4) {
    wait_slots(fle + t * 16, 8, tid);
    __syncthreads();
    // copy (layout-preserving) h_enc slot t+1 into LDS
    {
      const uint4* s = (const uint4*)(h_enc + (size_t)(t + 1) * 32 * 256);
      for (int i = tid; i < 1024; i += 256) ((uint4*)Abuf)[i] = s[i];
    }
    __syncthreads();
    f32x16v acc = {};
#pragma unroll
    for (int ks = 0; ks < 4; ++ks) {
      int k = (ks0 + ks) * 16 + hsel * 8;
      bf16x8 a = *(const bf16x8*)(Abuf + ln31 * 256 + ((((k >> 3) ^ (ln31 & 7)) << 3)));
      acc = __builtin_amdgcn_mfma_f32_32x32x16_bf16(a, Wreg[ks], acc, 0, 0, 0);
    }
    float* pp = partial + (wv * 32 + ln31) * 33 + 4 * hsel;
#pragma unroll
    for (int q = 0; q < 4; ++q)
#pragma unroll
      for (int s = 0; s < 4; ++s)
        pp[8 * q + s] = acc[4 * q + s];
    __syncthreads();
    for (int p = tid; p < 512; p += 256) {
      int m = p >> 4, np = (p & 15) * 2;
      float v[2];
#pragma unroll
      for (int j = 0; j < 2; ++j) {
        int col = np + j;
        float s = partial[col * 33 + m] + partial[(32 + col) * 33 + m]
                + partial[(64 + col) * 33 + m] + partial[(96 + col) * 33 + m] + emb_b[col];
        v[j] = fmaxf(s, 0.f);
      }
      int k = 256 + np;
      int pos = ((((k >> 3) ^ (m & 7)) << 3)) + (k & 7);
      store_pair_at(hidden, (size_t)(t * 32 + m) * 512 + pos, v[0], v[1]);
    }
    __syncthreads();
    if (tid == 0) post_slot(flb + t * 16);
  }
}

// ---- heads: logits, log_softmax, entropy, value
__device__ void heads_body(const bf16* __restrict__ h3, const float* __restrict__ actor_w,
    const float* __restrict__ actor_b, const float* __restrict__ critic_w,
    const float* __restrict__ critic_b, const int* __restrict__ action,
    float* __restrict__ out, int* fl3, int t0, int tid, char* smem)
{
  float* hS = (float*)smem;       // [32][520]
  float* lg = hS + 32 * 520;      // [32][8]
  float* vp = lg + 256;           // [32][8]
  const int b = tid >> 3, c = tid & 7;
  for (int t = t0; t < 64; t += 8) {
    wait_slots(fl3 + t * 16, 16, tid);
    __syncthreads();
    for (int i = tid; i < 2048; i += 256) {
      int m = i >> 6, j = i & 63;   // logical chunk j
      bf16x8 v = *(const bf16x8*)(h3 + ((size_t)(t + 1) * 32 + m) * 512 +
                                  ((j ^ (m & 7)) << 3));
#pragma unroll
      for (int q = 0; q < 8; ++q) hS[m * 520 + j * 8 + q] = (float)v[q];
    }
    __syncthreads();
    float acc = actor_b[c];
    float va = 0.f;
#pragma unroll 4
    for (int k = 0; k < 512; k += 4) {
      f32x4v hv = *(const f32x4v*)(hS + b * 520 + k);
      f32x4v wv4 = *(const f32x4v*)(actor_w + c * 512 + k);
      acc += hv[0]*wv4[0] + hv[1]*wv4[1] + hv[2]*wv4[2] + hv[3]*wv4[3];
    }
    for (int k = c * 64; k < c * 64 + 64; k += 4) {
      f32x4v hv = *(const f32x4v*)(hS + b * 520 + k);
      f32x4v wv4 = *(const f32x4v*)(critic_w + k);
      va += hv[0]*wv4[0] + hv[1]*wv4[1] + hv[2]*wv4[2] + hv[3]*wv4[3];
    }
    lg[b * 8 + c] = acc;
    vp[b * 8 + c] = va;
    __syncthreads();
    if (tid < 32) {
      const float* L = lg + tid * 8;
      float mx = L[0];
#pragma unroll
      for (int i = 1; i < 8; ++i) mx = fmaxf(mx, L[i]);
      float s = 0.f;
#pragma unroll
      for (int i = 0; i < 8; ++i) s += __expf(L[i] - mx);
      float lse = mx + __logf(s);
      float ent = 0.f;
#pragma unroll
      for (int i = 0; i < 8; ++i) { float lp = L[i] - lse; ent -= __expf(lp) * lp; }
      int a = action[t * 32 + tid];
      a = a < 0 ? 0 : (a > 7 ? 7 : a);
      float val = critic_b[0];
#pragma unroll
      for (int i = 0; i < 8; ++i) val += vp[tid * 8 + i];
      float* o = out + (size_t)(t * 32 + tid) * 3;
      o[0] = L[a] - lse; o[1] = ent; o[2] = val;
    }
    __syncthreads();
  }
}

struct PipeP {
  const bf16 *Wenc, *Wm0, *Wm1, *Wm2, *Wm3, *Wemb;
  const float *pre_enc, *bc, *done, *emb_b, *enc_c0, *mem_c0;
  bf16 *hidden, *h_enc, *h_mem;
  const float *actor_w, *actor_b, *critic_w, *critic_b;
  const int *action;
  float *out;
  int *fl;
};

// flag ints: mem l: (l*64+t)*16+s (16 slots); enc: (256+t)*16+s (8); emb: (320+t)*16
// grid: 0..63 mem (16 x 4 layers), 64..71 enc, 72..75 emb, 76..83 heads
__global__ __launch_bounds__(256, 1) void pipeline_kernel(PipeP P) {
  extern __shared__ char smem[];
  const int bid = blockIdx.x, tid = threadIdx.x;
  int* fl = P.fl;
  if (bid < 64) {
    int l = bid >> 4, s = bid & 15, u0 = s * 32;
    bf16* hown = P.h_mem + (size_t)l * HM_ELEMS;
    const bf16* W = (l == 0) ? P.Wm0 : (l == 1) ? P.Wm1 : (l == 2) ? P.Wm2 : P.Wm3;
    const bf16* xb = (l == 0) ? P.hidden : P.h_mem + (size_t)(l - 1) * HM_ELEMS + 32 * 512;
    int* fown = fl + l * 1024;
    int* fx = (l == 0) ? fl + 320 * 16 : fl + (l - 1) * 1024;
    int nx = (l == 0) ? 1 : 16;
    scan_body<2, 512, false>(W, P.bc + l * 2048, xb, hown, hown,
        P.mem_c0 + l * 32 * 512, P.done, fown, 16, fx, nx, s, u0, tid, smem);
  } else if (bid < 72) {
    int s = bid - 64, u0 = s * 32;
    scan_body<1, 256, true>(P.Wenc, P.pre_enc, nullptr, P.h_enc, P.h_enc,
        P.enc_c0, P.done, fl + 256 * 16, 8, nullptr, 0, s, u0, tid, smem);
  } else if (bid < 76) {
    emb_body(P.Wemb, P.emb_b, P.h_enc, P.hidden, fl + 256 * 16, fl + 320 * 16,
             bid - 72, tid, smem);
  } else {
    heads_body(P.h_mem + 3ull * HM_ELEMS, P.actor_w, P.actor_b, P.critic_w, P.critic_b,
        P.action, P.out, fl + 3 * 1024, bid - 76, tid, smem);
  }
}

// ---------------------------------------------------------------------------
// prep (+ pre_enc merged): vectorized weight conversions / swizzled h0 slots.
// blocks [0, 4466): prep; [4466, 12658): pre_enc.
// ---------------------------------------------------------------------------
__device__ __forceinline__ void cvt_store8(bf16* dst, const float* src) {
  f32x4v a = *(const f32x4v*)src, b = *(const f32x4v*)(src + 4);
  bf16x8 o;
#pragma unroll
  for (int j = 0; j < 4; ++j) { o[j] = (bf16)a[j]; o[4 + j] = (bf16)b[j]; }
  *(bf16x8*)dst = o;
}

__global__ void prep_preenc_kernel(
    const float* __restrict__ enc_Whh, const float* __restrict__ mem_Wih0,
    const float* __restrict__ mem_WihR, const float* __restrict__ mem_Whh,
    const float* __restrict__ emb_w, const float* __restrict__ mem_bih,
    const float* __restrict__ mem_bhh, const float* __restrict__ enc_h0,
    const float* __restrict__ mem_h0, const float* __restrict__ fc_w,
    const float* __restrict__ conv1_w,
    bf16* __restrict__ Wenc, bf16* __restrict__ Wm0, bf16* __restrict__ Wm123,
    bf16* __restrict__ Wemb, float* __restrict__ bc,
    bf16* __restrict__ h_enc, bf16* __restrict__ h_mem, bf16* __restrict__ fcw_bf,
    bf16* __restrict__ w1bf,
    const float* __restrict__ lang, const float* __restrict__ enc_Wih,
    const float* __restrict__ enc_bih, const float* __restrict__ enc_bhh,
    float* __restrict__ preenc)
{
  if (blockIdx.x >= 4466) {   // ---- pre_enc part ----
    int idx = (blockIdx.x - 4466) * 256 + threadIdx.x;
    if (idx >= 64 * 32 * 1024) return;
    int col = idx & 1023, bm = idx >> 10;
    float acc = enc_bih[col] + enc_bhh[col];
    const float* lp = lang + bm * 14;
    const float* wp = enc_Wih + col * 14;
#pragma unroll
    for (int k = 0; k < 14; ++k) acc += lp[k] * wp[k];
    preenc[idx] = acc;
    return;
  }
  int v = blockIdx.x * 256 + threadIdx.x;   // 8-elem vector index
  if (v < 32768) { cvt_store8(Wenc + v * 8, enc_Whh + v * 8); return; }
  v -= 32768;
  if (v < 262144) {   // Wm0 [2048 cols][1024 k]: 288 Wih0 | 224 zero | 512 Whh
    int col = v >> 7, c = v & 127;
    bf16x8 o = {};
    if (c < 36) {
      const float* s = mem_Wih0 + col * 288 + c * 8;
#pragma unroll
      for (int j = 0; j < 8; ++j) o[j] = (bf16)s[j];
    } else if (c >= 64) {
      const float* s = mem_Whh + col * 512 + (c - 64) * 8;
#pragma unroll
      for (int j = 0; j < 8; ++j) o[j] = (bf16)s[j];
    }
    *(bf16x8*)(Wm0 + (size_t)v * 8) = o;
    return;
  }
  v -= 262144;
  if (v < 786432) {   // Wm1..3 [l][2048 cols][1024 k]: 512 WihR | 512 Whh
    int l = v >> 18, r = v & 262143, col = r >> 7, c = r & 127;
    const float* s = (c < 64) ? mem_WihR + ((size_t)(l * 2048 + col)) * 512 + c * 8
                              : mem_Whh + ((size_t)((l + 1) * 2048 + col)) * 512 + (c - 64) * 8;
    cvt_store8(Wm123 + (size_t)v * 8, s);
    return;
  }
  v -= 786432;
  if (v < 1024) { cvt_store8(Wemb + v * 8, emb_w + v * 8); return; }
  v -= 1024;
  if (v < 1024) {
#pragma unroll
    for (int j = 0; j < 8; ++j) bc[v * 8 + j] = mem_bih[v * 8 + j] + mem_bhh[v * 8 + j];
    return;
  }
  v -= 1024;
  if (v < 1024) {     // h_enc slot 0 (swizzled)
    int m = v >> 5, c = v & 31;
    bf16x8 o;
    const float* s = enc_h0 + m * 256 + c * 8;
#pragma unroll
    for (int j = 0; j < 8; ++j) o[j] = (bf16)s[j];
    *(bf16x8*)(h_enc + m * 256 + ((c ^ (m & 7)) << 3)) = o;
    return;
  }
  v -= 1024;
  if (v < 8192) {     // h_mem slot 0 per layer (swizzled)
    int l = v >> 11, r = v & 2047, m = r >> 6, c = r & 63;
    bf16x8 o;
    const float* s = mem_h0 + ((size_t)(l * 32 + m)) * 512 + c * 8;
#pragma unroll
    for (int j = 0; j < 8; ++j) o[j] = (bf16)s[j];
    *(bf16x8*)(h_mem + (size_t)l * HM_ELEMS + m * 512 + ((c ^ (m & 7)) << 3)) = o;
    return;
  }
  v -= 8192;
  if (v < 50176) { cvt_store8(fcw_bf + (size_t)v * 8, fc_w + (size_t)v * 8); return; }
  v -= 50176;
  if (v < 512) {      // conv1 weights [16 oc][256 k] zero-padded
    int oc = v >> 5, c = v & 31;
    bf16x8 o = {};
#pragma unroll
    for (int j = 0; j < 8; ++j) {
      int k = c * 8 + j;
      if (k < 243) o[j] = (bf16)conv1_w[oc * 243 + k];
    }
    *(bf16x8*)(w1bf + v * 8) = o;
    return;
  }
}

// ---------------------------------------------------------------------------
// conv1 as MFMA GEMM (stride 9 == kernel 9 -> disjoint patches)
// ---------------------------------------------------------------------------
__global__ __launch_bounds__(256) void conv1_mfma(const float* __restrict__ img,
    const bf16* __restrict__ w1bf, const float* __restrict__ bias, float* __restrict__ out) {
  __shared__ bf16 sP[128 * 256];
  const int n = blockIdx.x, tid = threadIdx.x;
  const int lane = tid & 63, wv = tid >> 6;
  for (int i = tid; i < 4096; i += 256) ((uint4*)sP)[i] = uint4{0u, 0u, 0u, 0u};
  __syncthreads();
  const float* ib = img + (size_t)n * 29403;
  for (int e = tid; e < 29403; e += 256) {
    int c = e / 9801, r = e - c * 9801;
    int h = r / 99, w = r - h * 99;
    int oh = h / 9, kh = h - oh * 9;
    int ow = w / 9, kw = w - ow * 9;
    int p = oh * 11 + ow;
    int k = c * 81 + kh * 9 + kw;
    sP[p * 256 + (k ^ ((p & 15) * 8))] = (bf16)ib[e];
  }
  __syncthreads();
  const int oc = lane & 15, kg = lane >> 4;
  bf16x8 bfr[8];
#pragma unroll
  for (int ks = 0; ks < 8; ++ks)
    bfr[ks] = *(const bf16x8*)(w1bf + oc * 256 + ks * 32 + kg * 8);
  const float bv = bias[oc];
#pragma unroll
  for (int mt2 = 0; mt2 < 2; ++mt2) {
    int mt = wv * 2 + mt2;
    int p = mt * 16 + (lane & 15);
    f32x4v acc = {};
#pragma unroll
    for (int ks = 0; ks < 8; ++ks) {
      int k0 = ks * 32 + kg * 8;
      bf16x8 a = *(const bf16x8*)(sP + p * 256 + (k0 ^ ((p & 15) * 8)));
      acc = __builtin_amdgcn_mfma_f32_16x16x32_bf16(a, bfr[ks], acc, 0, 0, 0);
    }
#pragma unroll
    for (int s = 0; s < 4; ++s) {
      int pm = mt * 16 + (lane >> 4) * 4 + s;
      if (pm < 121)
        out[((size_t)n * 16 + oc) * 121 + pm] = fmaxf(acc[s] + bv, 0.f);
    }
  }
}

// ---------------------------------------------------------------------------
// conv2 + conv3 + fc fused. One block per image; A2 stays in LDS.
// Weight LDS strides PADDED: conv2 145 (bank stride 17, odd -> conflict-free),
// conv3 297 (bank stride 9, odd -> conflict-free). Old 144/288 were 16/32-way.
// Last finisher per 32-image slice (cnt acq-rel) runs the fc GEMM for that
// slice and writes hidden[:, :256] directly (swizzled), no extra LDS.
// ---------------------------------------------------------------------------
__device__ void fc_slice(int t, const bf16* __restrict__ a3bf,
    const bf16* __restrict__ wbf, const float* __restrict__ fc_b,
    bf16* __restrict__ hidden, int tid, char* smem)
{
  // stride 120 bf16 (240B): 16B-aligned rows, 4-way worst-case bank aliasing
  bf16* sA = (bf16*)smem;                 // [32][120]
  bf16* sB = sA + 32 * 120;               // [256][120]
  const int lane = tid & 63, wv = tid >> 6, hsel = lane >> 5, ln31 = lane & 31;
  f32x16v acc0 = {}, acc1 = {};
  for (int kb = 0; kb < 1568; kb += 112) {
    __syncthreads();
    for (int i = tid; i < 448; i += 256) {
      int r = i / 14, kk = (i % 14) * 8;
      *(bf16x8*)(sA + r * 120 + kk) =
          *(const bf16x8*)(a3bf + ((size_t)(t * 32 + r)) * 1568 + kb + kk);
    }
    for (int i = tid; i < 3584; i += 256) {
      int c = i / 14, kk = (i % 14) * 8;
      *(bf16x8*)(sB + c * 120 + kk) =
          *(const bf16x8*)(wbf + (size_t)c * 1568 + kb + kk);
    }
    __syncthreads();
#pragma unroll
    for (int kt = 0; kt < 7; ++kt) {
      int k = kt * 16 + hsel * 8;
      bf16x8 a  = *(const bf16x8*)(sA + ln31 * 120 + k);
      bf16x8 b0 = *(const bf16x8*)(sB + (wv * 64 + ln31) * 120 + k);
      bf16x8 b1 = *(const bf16x8*)(sB + (wv * 64 + 32 + ln31) * 120 + k);
      acc0 = __builtin_amdgcn_mfma_f32_32x32x16_bf16(a, b0, acc0, 0, 0, 0);
      acc1 = __builtin_amdgcn_mfma_f32_32x32x16_bf16(a, b1, acc1, 0, 0, 0);
    }
  }
  // C/D: col = lane&31 (B rows = output cols), m = 8q+4hsel+s (A rows = images)
  int cc0 = wv * 64 + ln31, cc1 = cc0 + 32;
  float bv0 = fc_b[cc0], bv1 = fc_b[cc1];
#pragma unroll
  for (int q = 0; q < 4; ++q)
#pragma unroll
    for (int s = 0; s < 4; ++s) {
      int m = 8 * q + 4 * hsel + s;
      size_t row = (size_t)(t * 32 + m) * 512;
      int p0 = ((((cc0 >> 3) ^ (m & 7)) << 3)) + (cc0 & 7);
      int p1 = ((((cc1 >> 3) ^ (m & 7)) << 3)) + (cc1 & 7);
      hidden[row + p0] = (bf16)fmaxf(acc0[4 * q + s] + bv0, 0.f);
      hidden[row + p1] = (bf16)fmaxf(acc1[4 * q + s] + bv1, 0.f);
    }
}

__global__ __launch_bounds__(256, 2) void conv23fc_kernel(
    const float* __restrict__ A1, const float* __restrict__ c2w,
    const float* __restrict__ c2b, const float* __restrict__ c3w,
    const float* __restrict__ c3b, const bf16* __restrict__ fcwbf,
    const float* __restrict__ fc_b, bf16* __restrict__ a3bf,
    bf16* __restrict__ hidden, int* __restrict__ cnt)
{
  __shared__ float sm[18672];     // 74.7 KB -> 2 blocks/CU
  float* sW2p = sm;               // [32][145]  (conv2 phase; aliased by A3L)
  float* A3L  = sm;               // [1568]     (conv3 phase, sW2p dead)
  float* sW3p = sm + 4640;        // [32][297]
  float* sIn  = sm + 14144;       // [16][121]
  float* A2L  = sm + 16080;       // [32][81]
  __shared__ int lastF;
  const int n = blockIdx.x, tid = threadIdx.x;
  // ---- stage weights (both convs, padded) + input tile ----
  for (int i = tid; i < 4608; i += 256) {
    int oc = i / 144, r = i - oc * 144;
    sW2p[oc * 145 + r] = c2w[i];
  }
  for (int i = tid; i < 9216; i += 256) {
    int oc = i / 288, r = i - oc * 288;
    sW3p[oc * 297 + r] = c3w[i];
  }
  for (int i = tid; i < 1936; i += 256) sIn[i] = A1[(size_t)n * 1936 + i];
  __syncthreads();
  // ---- conv2: 32 oc x 9 oh tasks ----
  for (int task = tid; task < 288; task += 256) {
    int oc = task & 31, oh = task >> 5;
    float acc[9];
    float bv = c2b[oc];
#pragma unroll
    for (int ow = 0; ow < 9; ++ow) acc[ow] = bv;
    for (int c = 0; c < 16; ++c) {
      const float* wr = sW2p + oc * 145 + c * 9;
      float wq[9];
#pragma unroll
      for (int q = 0; q < 9; ++q) wq[q] = wr[q];
#pragma unroll
      for (int kh = 0; kh < 3; ++kh) {
        const float* ir = sIn + c * 121 + (oh + kh) * 11;
        float iv[11];
#pragma unroll
        for (int q = 0; q < 11; ++q) iv[q] = ir[q];
#pragma unroll
        for (int ow = 0; ow < 9; ++ow)
          acc[ow] += wq[kh*3]*iv[ow] + wq[kh*3+1]*iv[ow+1] + wq[kh*3+2]*iv[ow+2];
      }
    }
#pragma unroll
    for (int ow = 0; ow < 9; ++ow)
      A2L[oc * 81 + oh * 9 + ow] = fmaxf(acc[ow], 0.f);
  }
  __syncthreads();
  // ---- conv3: 32 oc x 7 oh tasks (A3L aliases dead sW2p) ----
  for (int task = tid; task < 224; task += 256) {
    int oc = task & 31, oh = task >> 5;
    float acc[7];
    float bv = c3b[oc];
#pragma unroll
    for (int ow = 0; ow < 7; ++ow) acc[ow] = bv;
    for (int c = 0; c < 32; ++c) {
      const float* wr = sW3p + oc * 297 + c * 9;
      float wq[9];
#pragma unroll
      for (int q = 0; q < 9; ++q) wq[q] = wr[q];
#pragma unroll
      for (int kh = 0; kh < 3; ++kh) {
        const float* ir = A2L + c * 81 + (oh + kh) * 9;
        float iv[9];
#pragma unroll
        for (int q = 0; q < 9; ++q) iv[q] = ir[q];
#pragma unroll
        for (int ow = 0; ow < 7; ++ow)
          acc[ow] += wq[kh*3]*iv[ow] + wq[kh*3+1]*iv[ow+1] + wq[kh*3+2]*iv[ow+2];
      }
    }
#pragma unroll
    for (int ow = 0; ow < 7; ++ow)
      A3L[oc * 49 + oh * 7 + ow] = fmaxf(acc[ow], 0.f);
  }
  __syncthreads();
  // ---- pack A3 row -> global bf16 ----
  for (int i = tid; i < 784; i += 256)
    store_pair_at(a3bf, (size_t)n * 1568 + 2 * i, A3L[2 * i], A3L[2 * i + 1]);
  __syncthreads();
  if (tid == 0)
    lastF = __hip_atomic_fetch_add(cnt + (n >> 5), 1, __ATOMIC_ACQ_REL, SCOPE_AGENT);
  __syncthreads();
  if (lastF != 31) return;
  fc_slice(n >> 5, a3bf, fcwbf, fc_b, hidden, tid, (char*)sm);
}

// ---------------------------------------------------------------------------
extern "C" void kernel_launch(void* const* d_in, const int* in_sizes, int n_in,
                              void* d_out, int out_size, void* d_ws, size_t ws_size,
                              hipStream_t stream)
{
  const float* img      = (const float*)d_in[0];
  const float* lang     = (const float*)d_in[1];
  const float* done     = (const float*)d_in[2];
  const int*   action   = (const int*)d_in[3];
  const float* enc_h0   = (const float*)d_in[4];
  const float* enc_c0   = (const float*)d_in[5];
  const float* mem_h0   = (const float*)d_in[6];
  const float* mem_c0   = (const float*)d_in[7];
  const float* conv1_w  = (const float*)d_in[8];
  const float* conv1_b  = (const float*)d_in[9];
  const float* conv2_w  = (const float*)d_in[10];
  const float* conv2_b  = (const float*)d_in[11];
  const float* conv3_w  = (const float*)d_in[12];
  const float* conv3_b  = (const float*)d_in[13];
  const float* fc_w     = (const float*)d_in[14];
  const float* fc_b     = (const float*)d_in[15];
  const float* enc_Wih  = (const float*)d_in[16];
  const float* enc_Whh  = (const float*)d_in[17];
  const float* enc_bih  = (const float*)d_in[18];
  const float* enc_bhh  = (const float*)d_in[19];
  const float* emb_w    = (const float*)d_in[20];
  const float* emb_b    = (const float*)d_in[21];
  const float* mem_Wih0 = (const float*)d_in[22];
  const float* mem_WihR = (const float*)d_in[23];
  const float* mem_Whh  = (const float*)d_in[24];
  const float* mem_bih  = (const float*)d_in[25];
  const float* mem_bhh  = (const float*)d_in[26];
  const float* actor_w  = (const float*)d_in[27];
  const float* actor_b  = (const float*)d_in[28];
  const float* critic_w = (const float*)d_in[29];
  const float* critic_b = (const float*)d_in[30];
  float* out = (float*)d_out;
  (void)in_sizes; (void)n_in; (void)out_size; (void)ws_size;

  char* wp = (char*)d_ws;
  auto alloc = [&](size_t b) { char* p = wp; wp += (b + 255) & ~(size_t)255; return p; };
  float* A1     = (float*)alloc(2048ull * 16 * 121 * 4);
  bf16*  hidden = (bf16*) alloc(2048ull * 512 * 2);          // [TB][512] swizzled, zero-pad
  float* preenc = (float*)alloc(64ull * 32 * 1024 * 4);
  bf16*  Wenc   = (bf16*) alloc(1024ull * 256 * 2);
  bf16*  Wm0    = (bf16*) alloc(2048ull * 1024 * 2);
  bf16*  Wm123  = (bf16*) alloc(3ull * 2048 * 1024 * 2);
  bf16*  Wemb   = (bf16*) alloc(32ull * 256 * 2);
  float* bc     = (float*)alloc(4ull * 2048 * 4);
  bf16*  h_enc  = (bf16*) alloc(65ull * 32 * 256 * 2);
  bf16*  h_mem  = (bf16*) alloc(4ull * HM_ELEMS * 2);
  bf16*  fcwbf  = (bf16*) alloc(256ull * 1568 * 2);
  bf16*  w1bf   = (bf16*) alloc(16ull * 256 * 2);
  bf16*  a3bf   = (bf16*) alloc(2048ull * 1568 * 2);         // conv3 output rows
  int*   fl     = (int*)  alloc(24832);                      // flags + cnt tail
  int*   cnt    = fl + 6144;                                 // [64] per-slice counters

  hipMemsetAsync(fl, 0, 24832, stream);
  hipMemsetAsync(hidden, 0, 2048ull * 512 * 2, stream);
  prep_preenc_kernel<<<4466 + 8192, 256, 0, stream>>>(
      enc_Whh, mem_Wih0, mem_WihR, mem_Whh, emb_w,
      mem_bih, mem_bhh, enc_h0, mem_h0, fc_w, conv1_w,
      Wenc, Wm0, Wm123, Wemb, bc, h_enc, h_mem, fcwbf, w1bf,
      lang, enc_Wih, enc_bih, enc_bhh, preenc);
  conv1_mfma<<<2048, 256, 0, stream>>>(img, w1bf, conv1_b, A1);
  conv23fc_kernel<<<2048, 256, 0, stream>>>(A1, conv2_w, conv2_b, conv3_w, conv3_b,
      fcwbf, fc_b, a3bf, hidden, cnt);

  PipeP P;
  P.Wenc = Wenc; P.Wm0 = Wm0; P.Wm1 = Wm123;
  P.Wm2 = Wm123 + 2048ull * 1024; P.Wm3 = Wm123 + 2ull * 2048 * 1024;
  P.Wemb = Wemb; P.pre_enc = preenc; P.bc = bc; P.done = done; P.emb_b = emb_b;
  P.enc_c0 = enc_c0; P.mem_c0 = mem_c0; P.hidden = hidden; P.h_enc = h_enc; P.h_mem = h_mem;
  P.actor_w = actor_w; P.actor_b = actor_b; P.critic_w = critic_w; P.critic_b = critic_b;
  P.action = action; P.out = out; P.fl = fl;

  (void)hipFuncSetAttribute((const void*)pipeline_kernel,
      hipFuncAttributeMaxDynamicSharedMemorySize, 137216);
  pipeline_kernel<<<84, 256, 137216, stream>>>(P);
}